// Round 10
// baseline (221.383 us; speedup 1.0000x reference)
//
#include <hip/hip_runtime.h>
#include <hip/hip_bf16.h>
#include <math.h>

#define BB 8
#define NN 2048
#define DD 1024
#define LL 128
#define MM (BB*NN)   // 16384

typedef _Float16 half8 __attribute__((ext_vector_type(8)));
typedef _Float16 half4 __attribute__((ext_vector_type(4)));
typedef __attribute__((ext_vector_type(4))) float floatx4;

__device__ __forceinline__ void glds16(const void* g, void* l) {
    __builtin_amdgcn_global_load_lds(
        (const __attribute__((address_space(1))) unsigned int*)g,
        (__attribute__((address_space(3))) unsigned int*)l, 16, 0, 0);
}

// ---------------- e_j -> fp16 (8192 blocks)
__global__ __launch_bounds__(256) void prep_ej(const float* __restrict__ e_j,
                                               _Float16* __restrict__ eh) {
    int i = blockIdx.x * 256 + threadIdx.x;
    const float4* xp = (const float4*)e_j + (size_t)i * 2;
    float4 v0 = xp[0], v1 = xp[1];
    half8 h;
    h[0] = (_Float16)v0.x; h[1] = (_Float16)v0.y;
    h[2] = (_Float16)v0.z; h[3] = (_Float16)v0.w;
    h[4] = (_Float16)v1.x; h[5] = (_Float16)v1.y;
    h[6] = (_Float16)v1.z; h[7] = (_Float16)v1.w;
    *(half8*)(eh + (size_t)i * 8) = h;
}

// ---------------- Wk -> fp16 (512 blocks)
__global__ __launch_bounds__(256) void prep_wk(const float* __restrict__ Wk,
                                               _Float16* __restrict__ wh) {
    int i = blockIdx.x * 256 + threadIdx.x;
    const float4* xp = (const float4*)Wk + (size_t)i * 2;
    float4 v0 = xp[0], v1 = xp[1];
    half8 h;
    h[0] = (_Float16)v0.x; h[1] = (_Float16)v0.y;
    h[2] = (_Float16)v0.z; h[3] = (_Float16)v0.w;
    h[4] = (_Float16)v1.x; h[5] = (_Float16)v1.y;
    h[6] = (_Float16)v1.z; h[7] = (_Float16)v1.w;
    *(half8*)(wh + (size_t)i * 8) = h;
}

// ---------------- q = e_i @ Wq^T (256 blocks; Wq read once, e_i in LDS)
__global__ __launch_bounds__(256) void prep_q(const float* __restrict__ e_i,
                                              const float* __restrict__ Wq,
                                              float* __restrict__ q) {
    __shared__ float us[BB][DD];
    int tid = threadIdx.x;
    for (int i = tid; i < BB * DD / 4; i += 256)
        ((float4*)&us[0][0])[i] = ((const float4*)e_i)[i];
    __syncthreads();
    int w = tid >> 6, lane = tid & 63;
    int d = blockIdx.x * 4 + w;
    float acc[8] = {0.f, 0.f, 0.f, 0.f, 0.f, 0.f, 0.f, 0.f};
    for (int e0 = 0; e0 < DD; e0 += 256) {
        float4 wv = *(const float4*)&Wq[(size_t)d * DD + e0 + lane * 4];
        #pragma unroll
        for (int r = 0; r < 8; ++r) {
            float4 uv = *(const float4*)&us[r][e0 + lane * 4];
            acc[r] += wv.x * uv.x + wv.y * uv.y + wv.z * uv.z + wv.w * uv.w;
        }
    }
    #pragma unroll
    for (int r = 0; r < 8; ++r) {
        float s = acc[r];
        #pragma unroll
        for (int off = 32; off; off >>= 1) s += __shfl_down(s, off, 64);
        if (lane == 0) q[r * DD + d] = s;
    }
}

// ---------------- heavy kernel: single-pass fp16 MFMA + 2-stage glds16 double-buffer
// 128x128 tile, BK=32; per wave-iter: 16 MFMA / 8 ds_read_b128 / 4 glds16.
// Prefetch for k+1 issued right after barrier k -> vmcnt(0) drain at barrier k+1
// waits on loads that have had a full iteration in flight.
__global__ __launch_bounds__(256) void sigma_mfma(const _Float16* __restrict__ eh,
                                                  const _Float16* __restrict__ wh,
                                                  const float* __restrict__ q,
                                                  const float* __restrict__ omega,
                                                  float* __restrict__ sig_part)   // [8][MM]
{
    __shared__ _Float16 Ah[2][128][32];   // 16 KB
    __shared__ _Float16 Bh[2][128][32];   // 16 KB
    __shared__ float red[128][2];

    const int tid  = threadIdx.x;
    const int lane = tid & 63;
    const int w    = tid >> 6;
    const int wr   = w >> 1, wc = w & 1;
    const int c15  = lane & 15, quad = lane >> 4;

    const int row0 = blockIdx.x * 128;
    const int col0 = blockIdx.y * 128;
    const int b    = row0 / NN;

    const int r0 = tid >> 2;            // 0..63
    const int ku = (tid & 3) * 8;       // k offset in halfs

    const _Float16* gA = eh + (size_t)(row0 + r0) * DD + ku;
    const _Float16* gB = wh + (size_t)(col0 + r0) * DD + ku;

    char* dA[2] = { (char*)&Ah[0][0][0] + w * 1024, (char*)&Ah[1][0][0] + w * 1024 };
    char* dB[2] = { (char*)&Bh[0][0][0] + w * 1024, (char*)&Bh[1][0][0] + w * 1024 };

    floatx4 acc[4][4];
    #pragma unroll
    for (int i = 0; i < 4; ++i)
        #pragma unroll
        for (int j = 0; j < 4; ++j)
            acc[i][j] = (floatx4){0.f, 0.f, 0.f, 0.f};

    // prologue: stage k0 = 0 into buffer 0
    glds16(gA,                   dA[0]);
    glds16(gA + (size_t)64 * DD, dA[0] + 4096);
    glds16(gB,                   dB[0]);
    glds16(gB + (size_t)64 * DD, dB[0] + 4096);

    for (int k0 = 0; k0 < DD; k0 += 32) {
        const int s = (k0 >> 5) & 1;
        __syncthreads();   // compiler emits vmcnt(0): buffer s landed; prev reads done
        if (k0 + 32 < DD) {
            const int n = s ^ 1;
            glds16(gA + k0 + 32,                   dA[n]);
            glds16(gA + (size_t)64 * DD + k0 + 32, dA[n] + 4096);
            glds16(gB + k0 + 32,                   dB[n]);
            glds16(gB + (size_t)64 * DD + k0 + 32, dB[n] + 4096);
        }

        half8 a[4], bf[4];
        #pragma unroll
        for (int i = 0; i < 4; ++i) {
            a[i]  = *(const half8*)&Ah[s][wr * 64 + i * 16 + c15][quad * 8];
            bf[i] = *(const half8*)&Bh[s][wc * 64 + i * 16 + c15][quad * 8];
        }
        #pragma unroll
        for (int i = 0; i < 4; ++i)
            #pragma unroll
            for (int j = 0; j < 4; ++j)
                acc[i][j] = __builtin_amdgcn_mfma_f32_16x16x32_f16(a[i], bf[j], acc[i][j], 0, 0, 0);
    }

    float part[4][4];
    #pragma unroll
    for (int i = 0; i < 4; ++i)
        #pragma unroll
        for (int r = 0; r < 4; ++r) part[i][r] = 0.f;

    #pragma unroll
    for (int j = 0; j < 4; ++j) {
        int c = col0 + wc * 64 + j * 16 + c15;
        float qv = q[b * DD + c];
        float om = omega[c];
        #pragma unroll
        for (int i = 0; i < 4; ++i)
            #pragma unroll
            for (int r = 0; r < 4; ++r)
                part[i][r] += tanhf(acc[i][j][r] + qv) * om;
    }
    #pragma unroll
    for (int i = 0; i < 4; ++i)
        #pragma unroll
        for (int r = 0; r < 4; ++r) {
            float s = part[i][r];
            s += __shfl_xor(s, 1, 64);
            s += __shfl_xor(s, 2, 64);
            s += __shfl_xor(s, 4, 64);
            s += __shfl_xor(s, 8, 64);
            if (c15 == 0) red[wr * 64 + i * 16 + quad * 4 + r][wc] = s;
        }
    __syncthreads();
    if (tid < 128)
        sig_part[blockIdx.y * MM + row0 + tid] = red[tid][0] + red[tid][1];
}

// ---------------- per-b softmax-style weights (64 blocks: 8 per b, full stats each)
__global__ __launch_bounds__(256) void softmax_k(const float* __restrict__ sig_part,
                                                 const float* __restrict__ imp,
                                                 float* __restrict__ a_ij) {
    int b = blockIdx.x >> 3, slice = blockIdx.x & 7;
    int tid = threadIdx.x;
    __shared__ float red[256];
    float sv[8];
    float m = -1e30f;
    #pragma unroll
    for (int p = 0; p < 8; ++p) {
        int n = p * 256 + tid;
        float s = 0.f;
        #pragma unroll
        for (int db = 0; db < 8; ++db) s += sig_part[db * MM + b * NN + n];
        sv[p] = s;
        m = fmaxf(m, s);
    }
    red[tid] = m; __syncthreads();
    for (int off = 128; off; off >>= 1) {
        if (tid < off) red[tid] = fmaxf(red[tid], red[tid + off]);
        __syncthreads();
    }
    m = red[0]; __syncthreads();
    float sum = 0.f;
    #pragma unroll
    for (int p = 0; p < 8; ++p) sum += expf(sv[p] - m);
    red[tid] = sum; __syncthreads();
    for (int off = 128; off; off >>= 1) {
        if (tid < off) red[tid] += red[tid + off];
        __syncthreads();
    }
    float inv = 1.f / (red[0] + 1e-9f * expf(-m));
    int n = slice * 256 + tid;
    a_ij[b * NN + n] = imp[b * NN + n] * expf(sv[slice] - m) * inv;
}

// ---------------- u partials from fp16 e_j: 1024 blocks, disjoint writes
__global__ __launch_bounds__(256) void u_kernel(const float* __restrict__ a_ij,
                                                const _Float16* __restrict__ eh,
                                                float* __restrict__ u_part) {
    int b = blockIdx.x >> 7, nc = blockIdx.x & 127;
    int t = threadIdx.x;
    float4 acc = {0.f, 0.f, 0.f, 0.f};
    const _Float16* base = eh + ((size_t)(b * NN + nc * 16)) * DD + t * 4;
    const float* ap = a_ij + b * NN + nc * 16;
    #pragma unroll
    for (int n = 0; n < 16; ++n) {
        float a = ap[n];
        half4 v = *(const half4*)(base + (size_t)n * DD);
        acc.x += a * (float)v[0]; acc.y += a * (float)v[1];
        acc.z += a * (float)v[2]; acc.w += a * (float)v[3];
    }
    *(float4*)(u_part + ((size_t)nc * BB + b) * DD + t * 4) = acc;
}

// ---------------- u[b,e] = sum over 128 partials
__global__ __launch_bounds__(256) void ureduce(const float* __restrict__ u_part,
                                               float* __restrict__ u) {
    int i = blockIdx.x * 256 + threadIdx.x;   // < 8192
    float s = 0.f;
    #pragma unroll 8
    for (int nc = 0; nc < 128; ++nc) s += u_part[(size_t)nc * BB * DD + i];
    u[i] = s;
}

// ---------------- A = X @ W^T with X cached in LDS; W read once (256 blocks)
__global__ __launch_bounds__(256) void rowdot8(const float* __restrict__ X,
                                               const float* __restrict__ W,
                                               float* __restrict__ out) {
    __shared__ float us[BB][DD];
    int tid = threadIdx.x;
    for (int i = tid; i < BB * DD / 4; i += 256)
        ((float4*)&us[0][0])[i] = ((const float4*)X)[i];
    __syncthreads();
    int w = tid >> 6, lane = tid & 63;
    int d = blockIdx.x * 4 + w;
    float acc[8] = {0.f, 0.f, 0.f, 0.f, 0.f, 0.f, 0.f, 0.f};
    for (int e0 = 0; e0 < DD; e0 += 256) {
        float4 wv = *(const float4*)&W[(size_t)d * DD + e0 + lane * 4];
        #pragma unroll
        for (int r = 0; r < 8; ++r) {
            float4 uv = *(const float4*)&us[r][e0 + lane * 4];
            acc[r] += wv.x * uv.x + wv.y * uv.y + wv.z * uv.z + wv.w * uv.w;
        }
    }
    #pragma unroll
    for (int r = 0; r < 8; ++r) {
        float s = acc[r];
        #pragma unroll
        for (int off = 32; off; off >>= 1) s += __shfl_down(s, off, 64);
        if (lane == 0) out[r * DD + d] = s;
    }
}

// ---------------- outputs: A, A_lk = A*R, A_l = A
__global__ __launch_bounds__(256) void out_kernel(const float* __restrict__ A,
                                                  const float* __restrict__ Rlk,
                                                  float* __restrict__ out) {
    int i = blockIdx.x * 256 + threadIdx.x;
    int d = i & (DD - 1);
    int l = (i >> 10) & (LL - 1);
    int b = i >> 17;
    out[BB * DD + i] = A[b * DD + d] * Rlk[l * DD + d];
    if (i < BB * DD) {
        out[i] = A[i];
        out[BB * DD + BB * LL * DD + i] = A[i];
    }
}

extern "C" void kernel_launch(void* const* d_in, const int* in_sizes, int n_in,
                              void* d_out, int out_size, void* d_ws, size_t ws_size,
                              hipStream_t stream) {
    const float* e_i   = (const float*)d_in[0];
    const float* e_j   = (const float*)d_in[1];
    const float* imp   = (const float*)d_in[2];
    const float* Rlk   = (const float*)d_in[3];
    const float* Wq    = (const float*)d_in[4];
    const float* Wk    = (const float*)d_in[5];
    const float* Wv    = (const float*)d_in[6];
    const float* omega = (const float*)d_in[7];
    float* out = (float*)d_out;
    float* ws  = (float*)d_ws;

    float* q    = ws;               // 8192
    float* sigp = ws + 8192;        // 131072
    float* a_ij = ws + 139264;      // 16384 (head reused as Abuf)
    float* u    = ws + 155648;      // 8192
    _Float16* eh = (_Float16*)(ws + 172032);      // MM*DD halfs = 32 MB
    _Float16* wh = eh + (size_t)MM * DD;          // 2 MB
    float* u_part = (float*)(wh + (size_t)DD * DD);  // 4 MB

    // 1) conversions + q (3 kernels; split for rocprof visibility)
    prep_ej<<<8192, 256, 0, stream>>>(e_j, eh);
    prep_wk<<<512, 256, 0, stream>>>(Wk, wh);
    prep_q<<<256, 256, 0, stream>>>(e_i, Wq, q);

    // 2) sigma partials: fp16 MFMA GEMM, double-buffered glds16 prefetch
    sigma_mfma<<<dim3(MM / 128, DD / 128), 256, 0, stream>>>(eh, wh, q, omega, sigp);

    // 3) a_ij
    softmax_k<<<64, 256, 0, stream>>>(sigp, imp, a_ij);

    // 4) u partials (no atomics) from fp16 e_j, then reduce
    u_kernel<<<1024, 256, 0, stream>>>(a_ij, eh, u_part);
    ureduce<<<32, 256, 0, stream>>>(u_part, u);

    // 5) A = u @ Wv^T (Wv read once; Abuf = a_ij head)
    rowdot8<<<256, 256, 0, stream>>>(u, Wv, a_ij);

    // 6) outputs
    out_kernel<<<(BB * LL * DD) / 256, 256, 0, stream>>>(a_ij, Rlk, out);
}